// Round 9
// baseline (363.241 us; speedup 1.0000x reference)
//
#include <hip/hip_runtime.h>
#include <hip/hip_bf16.h>

// Problem constants
#define N_ATOM 2000
#define MNBR   12
#define OFEA   92
#define AF     64
#define BFEA   41
#define K1     169   // 2A+B
#define O1     128
#define OE     82
#define NM     24000
#define NCONV  3
#define HID    128
#define NCRY   64
#define EPS_BN 1e-5f

#define LDA_T  192   // bf16 weight leading dim (169 padded to 192)
#define LDH    512   // REST: [h(0..127)|he(128..209)|pad|P'(256..383)|Q'(384..511)]
#define LDSW   88    // LDS row pitch (ushorts) for MFMA tiles
#define LDE    48    // padded E stride (41 -> 48)
#define LDD    132   // dump tile pitch (floats); 132%32=4, 16B-aligned rows

typedef __bf16 bf16x8 __attribute__((ext_vector_type(8)));
typedef float  f32x4  __attribute__((ext_vector_type(4)));

__device__ __forceinline__ float sigmoidf_(float x){
    return __builtin_amdgcn_rcpf(1.f + __expf(-x));
}
__device__ __forceinline__ float softplusf_(float x){
    return fmaxf(x,0.f) + __logf(1.f + __expf(-fabsf(x)));
}

// ================= bf16 MFMA GEMM (A from bf16 mirrors) + fused BN stats.
// Epilogue v2: acc -> LDS dump tile (2 half-passes over dead As/Ws) ->
// float4 REST stores + atomic-free column stats + exclusive-column spa.
// STL layout (floats): S1A[0..255] S2A[256..511] S13[512..639] S23[640..767]
//   S12[768..831] S22[832..895] S2P[896..1023] S2Q[1024..1151] cnt[1200]
__global__ __launch_bounds__(256, 3)
void gemm_fused(const unsigned short* __restrict__ Xb,
                const unsigned short* __restrict__ E48b,
                const int*   __restrict__ idx,
                const __hip_bfloat16* __restrict__ W,
                const float* __restrict__ bias,
                float* __restrict__ REST,
                float* __restrict__ STL,
                float* __restrict__ SPA,
                float* __restrict__ SQA)
{
    __shared__ __align__(16) char smem_u[45056];   // As+Ws  |  dump[64][132]
    unsigned short (*As)[LDSW] = (unsigned short(*)[LDSW])smem_u;
    unsigned short (*Ws)[LDSW] = (unsigned short(*)[LDSW])(smem_u + 22528);
    float (*dump)[LDD] = (float(*)[LDD])smem_u;
    __shared__ float spa[12][128];   // per-atom P'/Q' row-sums (exclusive per col)

    const int tid  = threadIdx.x;
    const int row0 = blockIdx.x * 128;
    const int col0 = blockIdx.y * 128;
    const int w    = tid >> 6;
    const int l    = tid & 63;
    const int wm   = w >> 1, wn = w & 1;
    const int lrow = l & 15;
    const int quad = l >> 4;

    for (int ii = tid; ii < 12*128; ii += 256) spa[ii>>7][ii&127] = 0.f;

    f32x4 acc[4][4];
    #pragma unroll
    for (int i=0;i<4;i++)
        #pragma unroll
        for (int j=0;j<4;j++) acc[i][j] = (f32x4){0.f,0.f,0.f,0.f};

    #pragma unroll
    for (int it = 0; it < 3; ++it){
        const int k0 = it * 64;
        if (it) __syncthreads();
        #pragma unroll
        for (int j = 0; j < 4; ++j){
            int e   = tid + j*256;
            int r   = e >> 3;
            int kk8 = (e & 7);            // group of 8 bf16
            int grow = row0 + r;
            uint4 va = make_uint4(0,0,0,0);
            if (grow < NM){
                if (it == 2){
                    if (kk8 < 6)
                        va = *(const uint4*)(E48b + (size_t)grow*LDE + kk8*8);
                } else {
                    const unsigned short* s = (it == 0)
                        ? Xb + (size_t)((unsigned)grow/12u)*AF + kk8*8
                        : Xb + (size_t)idx[grow]*AF + kk8*8;
                    va = *(const uint4*)s;
                }
            }
            *(uint4*)(&As[r][kk8*8]) = va;
            uint4 vw = *(const uint4*)(W + (size_t)(col0 + r)*LDA_T + k0 + kk8*8);
            *(uint4*)(&Ws[r][kk8*8]) = vw;
        }
        __syncthreads();
        #pragma unroll
        for (int ks = 0; ks < 2; ++ks){
            int koff = ks*32 + quad*8;
            bf16x8 a_[4], b_[4];
            #pragma unroll
            for (int mi=0;mi<4;mi++)
                a_[mi] = *(const bf16x8*)(&As[wm*64 + mi*16 + lrow][koff]);
            #pragma unroll
            for (int ni=0;ni<4;ni++)
                b_[ni] = *(const bf16x8*)(&Ws[wn*64 + ni*16 + lrow][koff]);
            #pragma unroll
            for (int mi=0;mi<4;mi++)
                #pragma unroll
                for (int ni=0;ni<4;ni++)
                    acc[mi][ni] = __builtin_amdgcn_mfma_f32_16x16x32_bf16(
                        a_[mi], b_[ni], acc[mi][ni], 0, 0, 0);
        }
    }

    // ---------------- epilogue v2 ----------------
    const bool isPQ  = (col0 >= 256);
    const int  rem12 = row0 % 12;
    float s1 = 0.f, s2 = 0.f;

    #pragma unroll
    for (int p = 0; p < 2; ++p){
        __syncthreads();                    // As/Ws (p=0) / prior dump (p=1) dead
        if (wm == p){
            #pragma unroll
            for (int mi=0;mi<4;mi++){
                #pragma unroll
                for (int ni=0;ni<4;ni++){
                    int lr = mi*16 + quad*4;
                    int cl = wn*64 + ni*16 + lrow;
                    float bv = bias[col0 + cl];
                    dump[lr+0][cl] = acc[mi][ni][0] + bv;
                    dump[lr+1][cl] = acc[mi][ni][1] + bv;
                    dump[lr+2][cl] = acc[mi][ni][2] + bv;
                    dump[lr+3][cl] = acc[mi][ni][3] + bv;
                }
            }
        }
        __syncthreads();
        // vectorized stores: thread -> (row, 32-col segment), 8x float4
        {
            int lr  = tid >> 2;
            int cs0 = (tid & 3) * 32;
            int grow = row0 + p*64 + lr;
            if (grow < NM){
                float* dst = REST + (size_t)grow*LDH + col0 + cs0;
                const float* srcr = dump[lr] + cs0;
                #pragma unroll
                for (int c8=0;c8<8;c8++)
                    *(float4*)(dst + c8*4) = *(const float4*)(srcr + c8*4);
            }
        }
        // stats + per-atom sums: thread < 128 owns one column exclusively
        if (tid < 128){
            const int c  = tid;
            const int x0 = p*64;
            float run = 0.f;
            int aiPrev = (rem12 + x0) / 12;
            for (int r = 0; r < 64; ++r){
                int grow = row0 + x0 + r;
                if (grow >= NM) break;
                float v = dump[r][c];
                s1 += v; s2 += v*v;
                if (isPQ){
                    int ai = (rem12 + x0 + r) / 12;       // 0..11
                    if (ai != aiPrev){ spa[aiPrev][c] += run; run = 0.f; aiPrev = ai; }
                    run += v;
                }
            }
            if (isPQ && run != 0.f) spa[aiPrev][c] += run;
        }
    }
    __syncthreads();
    if (!isPQ){
        if (tid < 128){
            atomicAdd(&STL[col0 + tid],       s1);   // S1A
            atomicAdd(&STL[256 + col0 + tid], s2);   // S2A
        }
    } else {
        if (tid < 128)
            atomicAdd(&STL[(col0 == 256 ? 896 : 1024) + tid], s2); // S2P / S2Q
        const int atomBase = row0 / 12;
        float* SPQd = (col0 == 256) ? SPA : SQA;
        for (int ii = tid; ii < 12*128; ii += 256){
            int ai = ii >> 7, c2 = ii & 127;
            int na = atomBase + ai;
            float val = spa[ai][c2];
            if (val != 0.f && na < N_ATOM)
                atomicAdd(&SPQd[(size_t)na*128 + c2], val);
        }
    }
}

// ================= fold per-atom P/Q sums into closed-form BN3 sums
__global__ __launch_bounds__(256)
void bn3_pre(const float* __restrict__ SPA, const float* __restrict__ SQA,
             float* __restrict__ STL)
{
    const int c    = threadIdx.x & 127;
    const int half = threadIdx.x >> 7;
    float s1 = 0.f, sx = 0.f;
    for (int n = blockIdx.x*2 + half; n < N_ATOM; n += 250){
        float p = SPA[(size_t)n*128 + c];
        float q = SQA[(size_t)n*128 + c];
        s1 += p + q;
        sx += p * q;
    }
    atomicAdd(&STL[512 + c], 12.f*s1);   // S13
    atomicAdd(&STL[640 + c], 2.f*sx);    // S23 cross term
}

// ================= embedding: X[2000][64] = atom_fea @ emb_W^T + b (fp32 + bf16 mirror)
__global__ __launch_bounds__(256)
void emb_k(const float* __restrict__ A, const float* __restrict__ Wm,
           const float* __restrict__ b, float* __restrict__ X,
           __hip_bfloat16* __restrict__ Xb)
{
    __shared__ float Ws[64][93];
    __shared__ float As[16][93];
    const int t = threadIdx.x;
    const int n0 = blockIdx.x * 16;
    for (int i = t; i < 64*OFEA; i += 256){
        int c = i / OFEA, k = i % OFEA;
        Ws[c][k] = Wm[i];
    }
    for (int i = t; i < 16*OFEA; i += 256){
        int r = i / OFEA, k = i % OFEA;
        As[r][k] = A[(size_t)(n0 + r)*OFEA + k];
    }
    __syncthreads();
    const int r  = t >> 4;
    const int c0 = (t & 15) * 4;
    float a0=0.f, a1=0.f, a2=0.f, a3=0.f;
    for (int k = 0; k < OFEA; ++k){
        float av = As[r][k];
        a0 += av * Ws[c0+0][k];
        a1 += av * Ws[c0+1][k];
        a2 += av * Ws[c0+2][k];
        a3 += av * Ws[c0+3][k];
    }
    size_t o = (size_t)(n0 + r)*AF + c0;
    float v0 = a0 + b[c0+0], v1 = a1 + b[c0+1];
    float v2 = a2 + b[c0+2], v3 = a3 + b[c0+3];
    X[o+0] = v0; X[o+1] = v1; X[o+2] = v2; X[o+3] = v3;
    Xb[o+0] = __float2bfloat16(v0); Xb[o+1] = __float2bfloat16(v1);
    Xb[o+2] = __float2bfloat16(v2); Xb[o+3] = __float2bfloat16(v3);
}

// ================= head: Z[2000][128] = softplus(softplus(X) @ fc1W^T + b)
__global__ __launch_bounds__(256)
void head_k(const float* __restrict__ X, const float* __restrict__ Wm,
            const float* __restrict__ b, float* __restrict__ Z)
{
    __shared__ float Ws[128][65];
    __shared__ float Xs[16][65];
    const int t = threadIdx.x;
    const int n0 = blockIdx.x * 16;
    for (int i = t; i < 128*AF; i += 256){
        int c = i >> 6, k = i & 63;
        Ws[c][k] = Wm[i];
    }
    for (int i = t; i < 16*AF; i += 256){
        int r = i >> 6, k = i & 63;
        Xs[r][k] = softplusf_(X[(size_t)(n0 + r)*AF + k]);
    }
    __syncthreads();
    const int r  = t >> 4;
    const int c0 = (t & 15) * 8;
    float acc[8];
    #pragma unroll
    for (int j=0;j<8;j++) acc[j] = 0.f;
    for (int k = 0; k < AF; ++k){
        float xv = Xs[r][k];
        #pragma unroll
        for (int j=0;j<8;j++)
            acc[j] += xv * Ws[c0+j][k];
    }
    size_t o = (size_t)(n0 + r)*HID + c0;
    #pragma unroll
    for (int j=0;j<8;j++)
        Z[o+j] = softplusf_(acc[j] + b[c0+j]);
}

// ================= prologue: weight pack + bias + E48/E48b init + stat zeroing
__global__ void prologue_k(const float* __restrict__ fcW, const float* __restrict__ eW,
                           const float* __restrict__ W3, const float* __restrict__ fcb,
                           const float* __restrict__ eb, const float* __restrict__ b3,
                           const float* __restrict__ nbr,
                           __hip_bfloat16* __restrict__ WALL, float* __restrict__ BIAS,
                           float* __restrict__ E48, __hip_bfloat16* __restrict__ E48b,
                           float* __restrict__ ZR)
{
    int i = blockIdx.x*blockDim.x + threadIdx.x;
    const int nW = NCONV*512*LDA_T;           // 294912
    const int nB = NCONV*512;                 // 1536
    const int nE = NM*LDE;                    // 1152000
    if (i < nW){
        int ll = i/(512*LDA_T), rem = i%(512*LDA_T);
        int c = rem/LDA_T, k = rem%LDA_T;
        float v = 0.f;
        if (c < O1){
            if (k < K1) v = fcW[((size_t)ll*O1 + c)*K1 + k];
        } else if (c < O1+OE){
            if (k < K1) v = eW[((size_t)ll*OE + (c-O1))*K1 + k];
        } else if (c >= 256 && c < 384){
            int o = c - 256;
            const float* W3l = W3 + (size_t)ll*O1*274;
            if (k < AF)                        v = 0.5f * W3l[(size_t)o*274 + k];          // Wa/2
            else if (k < 2*AF)                 v = W3l[(size_t)o*274 + k];                 // Wj
            else if (k < K1)                   v = W3l[(size_t)o*274 + 192 + (k-128)];     // Wij
        } else if (c >= 384){
            int o = c - 384;
            const float* W3l = W3 + (size_t)ll*O1*274;
            if (k < AF)                        v = 0.5f * W3l[(size_t)o*274 + k];          // Wa/2
            else if (k < 2*AF)                 v = W3l[(size_t)o*274 + k + AF];            // Wl
            else if (k < K1)                   v = W3l[(size_t)o*274 + 233 + (k-128)];     // Wil
        }
        WALL[i] = __float2bfloat16(v);
    } else if (i < nW + nB){
        int m = i - nW;
        int ll = m/512, c = m%512;
        float v = 0.f;
        if (c < O1)         v = fcb[ll*O1 + c];
        else if (c < O1+OE) v = eb[ll*OE + (c-O1)];
        else if (c >= 256)  v = 0.5f * b3[ll*O1 + ((c-256)&127)];
        BIAS[m] = v;
    } else if (i < nW + nB + nE){
        int j = i - (nW + nB);
        int r = j / LDE, k = j % LDE;
        float v = (k < BFEA) ? nbr[(size_t)r*BFEA + k] : 0.f;
        E48[j]  = v;
        E48b[j] = __float2bfloat16(v);
    } else {
        int j = i - (nW + nB + nE);     // < 1,543,168
        ZR[j] = 0.f;
    }
}

// ================= consumer: block = atom, 256 threads (4 waves x 3 m's each).
// Inlined BN finalize; upfront 36-load prefetch (max MLP); factored exps.
__global__ __launch_bounds__(256)
void consumer_k(const float* __restrict__ REST, const float* __restrict__ STL,
                float* __restrict__ TB, float* __restrict__ E48,
                __hip_bfloat16* __restrict__ E48b,
                const float* __restrict__ g1, const float* __restrict__ b1,
                const float* __restrict__ ge, const float* __restrict__ be,
                const float* __restrict__ g3, const float* __restrict__ b3b)
{
    __shared__ float red[256];
    __shared__ float scA[210], shA[210], sc3v[128], sh3v[128];
    const int n = blockIdx.x;
    const int t = threadIdx.x;
    const int a = t & 63;
    const int g = t >> 6;     // 0..3, each owns 3 m's

    // ---- BN finalize (redundant per block; trivial ALU) ----
    if (t < 210){
        float mean = STL[t]*(1.f/NM);
        float var  = fmaxf(STL[256+t]*(1.f/NM) - mean*mean, 0.f);
        float gg = (t < O1) ? g1[t] : ge[t-O1];
        float bb = (t < O1) ? b1[t] : be[t-O1];
        float sc = gg * rsqrtf(var + EPS_BN);
        scA[t] = sc; shA[t] = bb - sc*mean;
    }
    if (t < 128){
        float inv  = 1.f/((float)NM*MNBR);
        float mean = STL[512+t]*inv;
        float ex2  = (STL[640+t] + 12.f*(STL[896+t] + STL[1024+t]))*inv;
        float var  = fmaxf(ex2 - mean*mean, 0.f);
        float sc = g3[t] * rsqrtf(var + EPS_BN);
        sc3v[t] = sc; sh3v[t] = b3b[t] - sc*mean;
    }
    __syncthreads();

    const float* base = REST + (size_t)n*MNBR*LDH;

    // ---- prefetch: all 36 independent loads issued before any exp ----
    float vQa[MNBR], vQb[MNBR];
    #pragma unroll
    for (int m=0;m<MNBR;m++){
        vQa[m] = base[(size_t)m*LDH + 384 + a];
        vQb[m] = base[(size_t)m*LDH + 448 + a];
    }
    float vh[3], vk[3], vP[3], vV[3];
    #pragma unroll
    for (int j=0;j<3;j++){
        const float* row = base + (size_t)(g*3+j)*LDH;
        vh[j] = row[a];
        vk[j] = row[64+a];
        vP[j] = row[256+a];
        vV[j] = row[320+a];
    }

    const float s3lo = sc3v[a],  s3hi = sc3v[64+a];
    const float t3lo = sh3v[a],  t3hi = sh3v[64+a];
    float Ea[MNBR], Fb[MNBR];
    #pragma unroll
    for (int m=0;m<MNBR;m++){
        Ea[m] = __expf(-(s3lo*vQa[m]));
        Fb[m] = __expf( (s3hi*vQb[m]));
    }
    const float sha = scA[a],    tha = shA[a];
    const float shb = scA[64+a], thb = shA[64+a];
    float acc = 0.f;
    #pragma unroll
    for (int j=0;j<3;j++){
        acc += sigmoidf_(sha*vh[j]+tha) * softplusf_(shb*vk[j]+thb);
        float ua = s3lo*vP[j] + t3lo;
        float ub = s3hi*vV[j] + t3hi;
        float Em = __expf(-ua);
        float Fm = __expf(ub);
        #pragma unroll
        for (int l2=0;l2<MNBR;l2++){
            float s = __builtin_amdgcn_rcpf(1.f + Em*Ea[l2]);
            float p = __logf(1.f + Fm*Fb[l2]);
            acc += s*p;
        }
    }
    red[t] = acc;
    __syncthreads();
    if (t < 64)
        TB[(size_t)n*AF + t] = red[t] + red[64+t] + red[128+t] + red[192+t];
    // edge update on padded E48 (+bf16 mirror for next layer's GEMM)
    for (int idx = t; idx < MNBR*BFEA; idx += 256){
        int m = idx / BFEA, b = idx % BFEA;
        const float* row = base + (size_t)m*LDH;
        float u = scA[O1+b]*row[O1+b]   + shA[O1+b];
        float v = scA[169+b]*row[169+b] + shA[169+b];
        size_t eo = ((size_t)n*MNBR + m)*LDE + b;
        float nv = E48[eo] + sigmoidf_(u) * softplusf_(v);
        E48[eo]  = nv;
        E48b[eo] = __float2bfloat16(nv);
    }
}

// ================= merged TB stats + x update (64 blocks, internal counter sync)
__global__ __launch_bounds__(256)
void xupd_k(float* __restrict__ X, __hip_bfloat16* __restrict__ Xb,
            const float* __restrict__ TB, float* __restrict__ STL,
            const float* __restrict__ g2, const float* __restrict__ b2)
{
    __shared__ float r1[256], r2[256];
    const int t = threadIdx.x;
    const int a = t & 63, rg = t >> 6;
    float s1 = 0.f, s2 = 0.f;
    for (int r = blockIdx.x*4 + rg; r < N_ATOM; r += 256){
        float v = TB[(size_t)r*AF + a];
        s1 += v; s2 += v*v;
    }
    r1[t] = s1; r2[t] = s2;
    __syncthreads();
    if (t < 64){
        s1 = r1[t]+r1[64+t]+r1[128+t]+r1[192+t];
        s2 = r2[t]+r2[64+t]+r2[128+t]+r2[192+t];
        atomicAdd(&STL[768+t], s1);
        atomicAdd(&STL[832+t], s2);
    }
    __syncthreads();
    if (t == 0){
        unsigned* cnt = (unsigned*)&STL[1200];
        __hip_atomic_fetch_add(cnt, 1u, __ATOMIC_ACQ_REL, __HIP_MEMORY_SCOPE_AGENT);
        while (__hip_atomic_load(cnt, __ATOMIC_ACQUIRE, __HIP_MEMORY_SCOPE_AGENT) < 64u)
            __builtin_amdgcn_s_sleep(2);
    }
    __syncthreads();
    float sA = __hip_atomic_load(&STL[768+a], __ATOMIC_RELAXED, __HIP_MEMORY_SCOPE_AGENT);
    float sB = __hip_atomic_load(&STL[832+a], __ATOMIC_RELAXED, __HIP_MEMORY_SCOPE_AGENT);
    float mean = sA*(1.f/N_ATOM);
    float var  = fmaxf(sB*(1.f/N_ATOM) - mean*mean, 0.f);
    float sc = g2[a]*rsqrtf(var + EPS_BN);
    float sh = b2[a] - sc*mean;
    for (int i = blockIdx.x*256 + t; i < N_ATOM*AF; i += 64*256){
        float v = softplusf_(X[i] + sc*TB[i] + sh);
        X[i]  = v;
        Xb[i] = __float2bfloat16(v);
    }
}

// ================= pooled mean per crystal + final dot
__global__ __launch_bounds__(128)
void pool_out_k(const float* __restrict__ Z, const int* __restrict__ seg,
                const float* __restrict__ outW, const float* __restrict__ outb,
                float* __restrict__ out)
{
    __shared__ float red[128];
    const int c = blockIdx.x;
    const int h = threadIdx.x;
    int l0, l1;
    {
        int l=0, r=N_ATOM;
        while (l<r){ int m=(l+r)>>1; if (seg[m] < c) l=m+1; else r=m; }
        l0 = l;
        l=l0; r=N_ATOM;
        while (l<r){ int m=(l+r)>>1; if (seg[m] < c+1) l=m+1; else r=m; }
        l1 = l;
    }
    float s = 0.f;
    for (int n = l0; n < l1; ++n) s += Z[(size_t)n*HID + h];
    float cnt = fmaxf((float)(l1-l0), 1.f);
    red[h] = (s/cnt) * outW[h];
    __syncthreads();
    for (int off=64; off>0; off>>=1){
        if (h < off) red[h] += red[h+off];
        __syncthreads();
    }
    if (h == 0) out[c] = red[0] + outb[0];
}

extern "C" void kernel_launch(void* const* d_in, const int* in_sizes, int n_in,
                              void* d_out, int out_size, void* d_ws, size_t ws_size,
                              hipStream_t stream)
{
    const float* atom_fea = (const float*)d_in[0];
    const float* nbr_fea  = (const float*)d_in[1];
    const int*   nbr_idx  = (const int*)d_in[2];
    const int*   site_seg = (const int*)d_in[3];
    const float* emb_W = (const float*)d_in[4];
    const float* emb_b = (const float*)d_in[5];
    const float* fcW   = (const float*)d_in[6];
    const float* fcb   = (const float*)d_in[7];
    const float* bn1_g = (const float*)d_in[8];
    const float* bn1_b = (const float*)d_in[9];
    const float* bn2_g = (const float*)d_in[10];
    const float* bn2_b = (const float*)d_in[11];
    const float* eW    = (const float*)d_in[12];
    const float* eb    = (const float*)d_in[13];
    const float* bne_g = (const float*)d_in[14];
    const float* bne_b = (const float*)d_in[15];
    const float* W3    = (const float*)d_in[16];
    const float* b3    = (const float*)d_in[17];
    const float* bn3_g = (const float*)d_in[18];
    const float* bn3_b = (const float*)d_in[19];
    const float* fc1W  = (const float*)d_in[20];
    const float* fc1b  = (const float*)d_in[21];
    const float* outW  = (const float*)d_in[22];
    const float* outb  = (const float*)d_in[23];

    // workspace layout (float units)
    float* ws   = (float*)d_ws;
    float* X    = ws;                          // 128,000
    float* E48  = ws + 128000;                 // 1,152,000 -> 1,280,000
    float* REST = ws + 1280000;                // 24000*512 = 12,288,000
    float* TB   = ws + 13568000;               // 128,000
    float* Z    = ws + 13696000;               // 256,000
    float* ST   = ws + 13952000;               // 3*2048 = 6,144
    //            ws + 13958144                // 1,024 spare (zeroed)
    float* SPQ  = ws + 13959168;               // 3 * 2 * 256,000 = 1,536,000
    __hip_bfloat16* WALL = (__hip_bfloat16*)(ws + 15495168); // 3*512*192 bf16
    float* BIAS = ws + 15642624;               // 1,536
    __hip_bfloat16* Xb   = (__hip_bfloat16*)(ws + 15644160); // 128,000 bf16
    __hip_bfloat16* E48b = (__hip_bfloat16*)(ws + 15708160); // 1,152,000 bf16

    {
        // flat prologue: 294,912 pack + 1,536 bias + 1,152,000 e_init + 1,543,168 zero
        const int total = 294912 + 1536 + 1152000 + 1543168;   // = 2,991,616
        prologue_k<<<total/256, 256, 0, stream>>>(fcW, eW, W3, fcb, eb, b3, nbr_fea,
                                                  WALL, BIAS, E48, E48b, ST);
    }
    emb_k<<<N_ATOM/16, 256, 0, stream>>>(atom_fea, emb_W, emb_b, X, Xb);

    for (int i = 0; i < NCONV; i++){
        float* STL = ST + i*2048;
        float* SPA = SPQ + (size_t)i*512000;
        float* SQA = SPA + 256000;

        {
            dim3 g((NM+127)/128, 4);
            gemm_fused<<<g, 256, 0, stream>>>((const unsigned short*)Xb,
                                              (const unsigned short*)E48b, nbr_idx,
                                              WALL + (size_t)i*512*LDA_T,
                                              BIAS + i*512, REST, STL, SPA, SQA);
        }
        bn3_pre<<<125, 256, 0, stream>>>(SPA, SQA, STL);
        consumer_k<<<N_ATOM, 256, 0, stream>>>(REST, STL, TB, E48, E48b,
                                               bn1_g + i*O1, bn1_b + i*O1,
                                               bne_g + i*OE, bne_b + i*OE,
                                               bn3_g + i*O1, bn3_b + i*O1);
        xupd_k<<<64, 256, 0, stream>>>(X, Xb, TB, STL,
                                       bn2_g + i*AF, bn2_b + i*AF);
    }

    // head: Z = softplus(softplus(X) @ fc1W^T + fc1b); pooled mean; out
    head_k<<<N_ATOM/16, 256, 0, stream>>>(X, fc1W, fc1b, Z);
    pool_out_k<<<NCRY, 128, 0, stream>>>(Z, site_seg, outW, outb, (float*)d_out);
}

// Round 10
// 355.238 us; speedup vs baseline: 1.0225x; 1.0225x over previous
//
#include <hip/hip_runtime.h>
#include <hip/hip_bf16.h>

// Problem constants
#define N_ATOM 2000
#define MNBR   12
#define OFEA   92
#define AF     64
#define BFEA   41
#define K1     169   // 2A+B
#define O1     128
#define OE     82
#define NM     24000
#define NCONV  3
#define HID    128
#define NCRY   64
#define EPS_BN 1e-5f

#define LDA_T  192   // bf16 weight leading dim (169 padded to 192)
#define LDH    512   // REST: [h(0..127)|he(128..209)|pad|P'(256..383)|Q'(384..511)]
#define LDSW   88    // LDS row pitch (ushorts) for MFMA tiles
#define LDE    48    // padded E stride (41 -> 48)

typedef __bf16 bf16x8 __attribute__((ext_vector_type(8)));
typedef float  f32x4  __attribute__((ext_vector_type(4)));

__device__ __forceinline__ float sigmoidf_(float x){
    return __builtin_amdgcn_rcpf(1.f + __expf(-x));
}
__device__ __forceinline__ float softplusf_(float x){
    return fmaxf(x,0.f) + __logf(1.f + __expf(-fabsf(x)));
}

// ================= bf16 MFMA GEMM: A-tile gathered directly from bf16 mirrors
// (Xb / E48b / idx); fused BN statistics in the epilogue (register-side,
// low-contention LDS atomics — R8-proven form).
// STL layout (floats): S1A[0..255] S2A[256..511] S13[512..639] S23[640..767]
//   S12[768..831] S22[832..895] S2P[896..1023] S2Q[1024..1151] cnt[1200]
__global__ __launch_bounds__(256, 3)
void gemm_fused(const unsigned short* __restrict__ Xb,
                const unsigned short* __restrict__ E48b,
                const int*   __restrict__ idx,
                const __hip_bfloat16* __restrict__ W,
                const float* __restrict__ bias,
                float* __restrict__ REST,
                float* __restrict__ STL,
                float* __restrict__ SPA,
                float* __restrict__ SQA)
{
    __shared__ unsigned short As[128][LDSW];
    __shared__ unsigned short Ws[128][LDSW];
    __shared__ float cs1[128];
    __shared__ float cs2[128];
    __shared__ float spa[12][128];   // per-atom P'/Q' row-sums (block spans <=12 atoms)

    const int tid  = threadIdx.x;
    const int row0 = blockIdx.x * 128;
    const int col0 = blockIdx.y * 128;
    const int w    = tid >> 6;
    const int l    = tid & 63;
    const int wm   = w >> 1, wn = w & 1;
    const int lrow = l & 15;
    const int quad = l >> 4;

    if (tid < 128){ cs1[tid] = 0.f; cs2[tid] = 0.f; }
    for (int ii = tid; ii < 12*128; ii += 256) spa[ii>>7][ii&127] = 0.f;

    f32x4 acc[4][4];
    #pragma unroll
    for (int i=0;i<4;i++)
        #pragma unroll
        for (int j=0;j<4;j++) acc[i][j] = (f32x4){0.f,0.f,0.f,0.f};

    #pragma unroll
    for (int it = 0; it < 3; ++it){
        const int k0 = it * 64;
        if (it) __syncthreads();
        #pragma unroll
        for (int j = 0; j < 4; ++j){
            int e   = tid + j*256;
            int r   = e >> 3;
            int kk8 = (e & 7);            // group of 8 bf16
            int grow = row0 + r;
            uint4 va = make_uint4(0,0,0,0);
            if (grow < NM){
                if (it == 2){
                    if (kk8 < 6)
                        va = *(const uint4*)(E48b + (size_t)grow*LDE + kk8*8);
                } else {
                    const unsigned short* s = (it == 0)
                        ? Xb + (size_t)((unsigned)grow/12u)*AF + kk8*8
                        : Xb + (size_t)idx[grow]*AF + kk8*8;
                    va = *(const uint4*)s;
                }
            }
            *(uint4*)(&As[r][kk8*8]) = va;
            uint4 vw = *(const uint4*)(W + (size_t)(col0 + r)*LDA_T + k0 + kk8*8);
            *(uint4*)(&Ws[r][kk8*8]) = vw;
        }
        __syncthreads();
        #pragma unroll
        for (int ks = 0; ks < 2; ++ks){
            int koff = ks*32 + quad*8;
            bf16x8 a_[4], b_[4];
            #pragma unroll
            for (int mi=0;mi<4;mi++)
                a_[mi] = *(const bf16x8*)(&As[wm*64 + mi*16 + lrow][koff]);
            #pragma unroll
            for (int ni=0;ni<4;ni++)
                b_[ni] = *(const bf16x8*)(&Ws[wn*64 + ni*16 + lrow][koff]);
            #pragma unroll
            for (int mi=0;mi<4;mi++)
                #pragma unroll
                for (int ni=0;ni<4;ni++)
                    acc[mi][ni] = __builtin_amdgcn_mfma_f32_16x16x32_bf16(
                        a_[mi], b_[ni], acc[mi][ni], 0, 0, 0);
        }
    }

    // ---------------- epilogue: store + fused BN stats ----------------
    const bool isPQ = (col0 >= 256);
    const int atomBase = (unsigned)row0 / 12u;
    int rbase_[4], n0_[4], sp_[4];
    #pragma unroll
    for (int mi=0;mi<4;mi++){
        rbase_[mi] = row0 + wm*64 + mi*16 + quad*4;
        int n0 = (int)((unsigned)rbase_[mi] / 12u);
        n0_[mi] = n0;
        sp_[mi] = 12 - (rbase_[mi] - n0*12);
    }

    #pragma unroll
    for (int ni=0;ni<4;ni++){
        const int cl  = wn*64 + ni*16 + lrow;   // 0..127 within block
        const int col = col0 + cl;
        const float bv = bias[col];
        float s1 = 0.f, s2 = 0.f;
        #pragma unroll
        for (int mi=0;mi<4;mi++){
            const int rbase = rbase_[mi];
            float run0 = 0.f, run1 = 0.f;
            #pragma unroll
            for (int reg=0;reg<4;reg++){
                int grow = rbase + reg;
                if (grow < NM){
                    float vv = acc[mi][ni][reg] + bv;
                    if (col0 != 128 || col < 210)     // cols 210..255 dead
                        REST[(size_t)grow*LDH + col] = vv;
                    s1 += vv; s2 += vv*vv;
                    if (isPQ){
                        if (reg < sp_[mi]) run0 += vv; else run1 += vv;
                    }
                }
            }
            if (isPQ){
                if (run0 != 0.f) atomicAdd(&spa[n0_[mi]     - atomBase][cl], run0);
                if (run1 != 0.f) atomicAdd(&spa[n0_[mi] + 1 - atomBase][cl], run1);
            }
        }
        if (isPQ){
            atomicAdd(&cs2[cl], s2);
        } else {
            atomicAdd(&cs1[cl], s1);
            atomicAdd(&cs2[cl], s2);
        }
    }
    __syncthreads();
    if (!isPQ){
        if (tid < 128){
            atomicAdd(&STL[col0 + tid],       cs1[tid]);   // S1A
            atomicAdd(&STL[256 + col0 + tid], cs2[tid]);   // S2A
        }
    } else {
        if (tid < 128)
            atomicAdd(&STL[(col0 == 256 ? 896 : 1024) + tid], cs2[tid]); // S2P / S2Q
        float* SPQd = (col0 == 256) ? SPA : SQA;
        for (int ii = tid; ii < 12*128; ii += 256){
            int ai = ii >> 7, c2 = ii & 127;
            int na = atomBase + ai;
            float val = spa[ai][c2];
            if (val != 0.f && na < N_ATOM)
                atomicAdd(&SPQd[(size_t)na*128 + c2], val);
        }
    }
}

// ================= fold per-atom P/Q sums into closed-form BN3 sums
__global__ __launch_bounds__(256)
void bn3_pre(const float* __restrict__ SPA, const float* __restrict__ SQA,
             float* __restrict__ STL)
{
    const int c    = threadIdx.x & 127;
    const int half = threadIdx.x >> 7;
    float s1 = 0.f, sx = 0.f;
    for (int n = blockIdx.x*2 + half; n < N_ATOM; n += 250){
        float p = SPA[(size_t)n*128 + c];
        float q = SQA[(size_t)n*128 + c];
        s1 += p + q;
        sx += p * q;
    }
    atomicAdd(&STL[512 + c], 12.f*s1);   // S13
    atomicAdd(&STL[640 + c], 2.f*sx);    // S23 cross term
}

// ================= embedding: X[2000][64] = atom_fea @ emb_W^T + b (fp32 + bf16 mirror)
__global__ __launch_bounds__(256)
void emb_k(const float* __restrict__ A, const float* __restrict__ Wm,
           const float* __restrict__ b, float* __restrict__ X,
           __hip_bfloat16* __restrict__ Xb)
{
    __shared__ float Ws[64][93];
    __shared__ float As[16][93];
    const int t = threadIdx.x;
    const int n0 = blockIdx.x * 16;
    for (int i = t; i < 64*OFEA; i += 256){
        int c = i / OFEA, k = i % OFEA;
        Ws[c][k] = Wm[i];
    }
    for (int i = t; i < 16*OFEA; i += 256){
        int r = i / OFEA, k = i % OFEA;
        As[r][k] = A[(size_t)(n0 + r)*OFEA + k];
    }
    __syncthreads();
    const int r  = t >> 4;
    const int c0 = (t & 15) * 4;
    float a0=0.f, a1=0.f, a2=0.f, a3=0.f;
    for (int k = 0; k < OFEA; ++k){
        float av = As[r][k];
        a0 += av * Ws[c0+0][k];
        a1 += av * Ws[c0+1][k];
        a2 += av * Ws[c0+2][k];
        a3 += av * Ws[c0+3][k];
    }
    size_t o = (size_t)(n0 + r)*AF + c0;
    float v0 = a0 + b[c0+0], v1 = a1 + b[c0+1];
    float v2 = a2 + b[c0+2], v3 = a3 + b[c0+3];
    X[o+0] = v0; X[o+1] = v1; X[o+2] = v2; X[o+3] = v3;
    Xb[o+0] = __float2bfloat16(v0); Xb[o+1] = __float2bfloat16(v1);
    Xb[o+2] = __float2bfloat16(v2); Xb[o+3] = __float2bfloat16(v3);
}

// ================= head: Z[2000][128] = softplus(softplus(X) @ fc1W^T + b)
__global__ __launch_bounds__(256)
void head_k(const float* __restrict__ X, const float* __restrict__ Wm,
            const float* __restrict__ b, float* __restrict__ Z)
{
    __shared__ float Ws[128][65];
    __shared__ float Xs[16][65];
    const int t = threadIdx.x;
    const int n0 = blockIdx.x * 16;
    for (int i = t; i < 128*AF; i += 256){
        int c = i >> 6, k = i & 63;
        Ws[c][k] = Wm[i];
    }
    for (int i = t; i < 16*AF; i += 256){
        int r = i >> 6, k = i & 63;
        Xs[r][k] = softplusf_(X[(size_t)(n0 + r)*AF + k]);
    }
    __syncthreads();
    const int r  = t >> 4;
    const int c0 = (t & 15) * 8;
    float acc[8];
    #pragma unroll
    for (int j=0;j<8;j++) acc[j] = 0.f;
    for (int k = 0; k < AF; ++k){
        float xv = Xs[r][k];
        #pragma unroll
        for (int j=0;j<8;j++)
            acc[j] += xv * Ws[c0+j][k];
    }
    size_t o = (size_t)(n0 + r)*HID + c0;
    #pragma unroll
    for (int j=0;j<8;j++)
        Z[o+j] = softplusf_(acc[j] + b[c0+j]);
}

// ================= prologue: weight pack + bias + E48/E48b init + stat zeroing
// flat index space: [0,nW) pack, [nW,nW+1536) bias, then e_init, then zero
__global__ void prologue_k(const float* __restrict__ fcW, const float* __restrict__ eW,
                           const float* __restrict__ W3, const float* __restrict__ fcb,
                           const float* __restrict__ eb, const float* __restrict__ b3,
                           const float* __restrict__ nbr,
                           __hip_bfloat16* __restrict__ WALL, float* __restrict__ BIAS,
                           float* __restrict__ E48, __hip_bfloat16* __restrict__ E48b,
                           float* __restrict__ ZR)
{
    int i = blockIdx.x*blockDim.x + threadIdx.x;
    const int nW = NCONV*512*LDA_T;           // 294912
    const int nB = NCONV*512;                 // 1536
    const int nE = NM*LDE;                    // 1152000
    if (i < nW){
        int ll = i/(512*LDA_T), rem = i%(512*LDA_T);
        int c = rem/LDA_T, k = rem%LDA_T;
        float v = 0.f;
        if (c < O1){
            if (k < K1) v = fcW[((size_t)ll*O1 + c)*K1 + k];
        } else if (c < O1+OE){
            if (k < K1) v = eW[((size_t)ll*OE + (c-O1))*K1 + k];
        } else if (c >= 256 && c < 384){
            int o = c - 256;
            const float* W3l = W3 + (size_t)ll*O1*274;
            if (k < AF)                        v = 0.5f * W3l[(size_t)o*274 + k];          // Wa/2
            else if (k < 2*AF)                 v = W3l[(size_t)o*274 + k];                 // Wj
            else if (k < K1)                   v = W3l[(size_t)o*274 + 192 + (k-128)];     // Wij
        } else if (c >= 384){
            int o = c - 384;
            const float* W3l = W3 + (size_t)ll*O1*274;
            if (k < AF)                        v = 0.5f * W3l[(size_t)o*274 + k];          // Wa/2
            else if (k < 2*AF)                 v = W3l[(size_t)o*274 + k + AF];            // Wl
            else if (k < K1)                   v = W3l[(size_t)o*274 + 233 + (k-128)];     // Wil
        }
        WALL[i] = __float2bfloat16(v);
    } else if (i < nW + nB){
        int m = i - nW;
        int ll = m/512, c = m%512;
        float v = 0.f;
        if (c < O1)         v = fcb[ll*O1 + c];
        else if (c < O1+OE) v = eb[ll*OE + (c-O1)];
        else if (c >= 256)  v = 0.5f * b3[ll*O1 + ((c-256)&127)];
        BIAS[m] = v;
    } else if (i < nW + nB + nE){
        int j = i - (nW + nB);
        int r = j / LDE, k = j % LDE;
        float v = (k < BFEA) ? nbr[(size_t)r*BFEA + k] : 0.f;
        E48[j]  = v;
        E48b[j] = __float2bfloat16(v);
    } else {
        int j = i - (nW + nB + nE);     // < 1,543,168
        ZR[j] = 0.f;
    }
}

// ================= consumer: block = atom, 256 threads (4 waves x 3 m's each).
// Inlined BN finalize; factored-exponential 3-body inner loop; bf16 E mirror.
__global__ __launch_bounds__(256)
void consumer_k(const float* __restrict__ REST, const float* __restrict__ STL,
                float* __restrict__ TB, float* __restrict__ E48,
                __hip_bfloat16* __restrict__ E48b,
                const float* __restrict__ g1, const float* __restrict__ b1,
                const float* __restrict__ ge, const float* __restrict__ be,
                const float* __restrict__ g3, const float* __restrict__ b3b)
{
    __shared__ float red[256];
    __shared__ float scA[210], shA[210], sc3v[128], sh3v[128];
    const int n = blockIdx.x;
    const int t = threadIdx.x;
    const int a = t & 63;
    const int g = t >> 6;     // 0..3, each owns 3 m's

    // ---- BN finalize (redundant per block; trivial ALU) ----
    if (t < 210){
        float mean = STL[t]*(1.f/NM);
        float var  = fmaxf(STL[256+t]*(1.f/NM) - mean*mean, 0.f);
        float gg = (t < O1) ? g1[t] : ge[t-O1];
        float bb = (t < O1) ? b1[t] : be[t-O1];
        float sc = gg * rsqrtf(var + EPS_BN);
        scA[t] = sc; shA[t] = bb - sc*mean;
    }
    if (t < 128){
        float inv  = 1.f/((float)NM*MNBR);
        float mean = STL[512+t]*inv;
        float ex2  = (STL[640+t] + 12.f*(STL[896+t] + STL[1024+t]))*inv;
        float var  = fmaxf(ex2 - mean*mean, 0.f);
        float sc = g3[t] * rsqrtf(var + EPS_BN);
        sc3v[t] = sc; sh3v[t] = b3b[t] - sc*mean;
    }
    __syncthreads();

    const float* base = REST + (size_t)n*MNBR*LDH;
    const float s3lo = sc3v[a],  s3hi = sc3v[64+a];
    const float t3lo = sh3v[a],  t3hi = sh3v[64+a];

    float Ea[MNBR], Fb[MNBR];
    #pragma unroll
    for (int m=0;m<MNBR;m++){
        const float* row = base + (size_t)m*LDH;
        Ea[m] = __expf(-(s3lo*row[384+a]));
        Fb[m] = __expf( (s3hi*row[448+a]));
    }
    const float sha = scA[a],    tha = shA[a];
    const float shb = scA[64+a], thb = shA[64+a];
    float acc = 0.f;
    #pragma unroll
    for (int j=0;j<3;j++){
        const float* row = base + (size_t)(g*3+j)*LDH;
        acc += sigmoidf_(sha*row[a]+tha) * softplusf_(shb*row[64+a]+thb);
        float ua = s3lo*row[256+a] + t3lo;
        float ub = s3hi*row[320+a] + t3hi;
        float Em = __expf(-ua);
        float Fm = __expf(ub);
        #pragma unroll
        for (int l2=0;l2<MNBR;l2++){
            float s = __builtin_amdgcn_rcpf(1.f + Em*Ea[l2]);
            float p = __logf(1.f + Fm*Fb[l2]);
            acc += s*p;
        }
    }
    red[t] = acc;
    __syncthreads();
    if (t < 64)
        TB[(size_t)n*AF + t] = red[t] + red[64+t] + red[128+t] + red[192+t];
    // edge update on padded E48 (+bf16 mirror for next layer's GEMM)
    for (int idx = t; idx < MNBR*BFEA; idx += 256){
        int m = idx / BFEA, b = idx % BFEA;
        const float* row = base + (size_t)m*LDH;
        float u = scA[O1+b]*row[O1+b]   + shA[O1+b];
        float v = scA[169+b]*row[169+b] + shA[169+b];
        size_t eo = ((size_t)n*MNBR + m)*LDE + b;
        float nv = E48[eo] + sigmoidf_(u) * softplusf_(v);
        E48[eo]  = nv;
        E48b[eo] = __float2bfloat16(nv);
    }
}

// ================= merged TB stats + x update (64 blocks, internal counter sync)
__global__ __launch_bounds__(256)
void xupd_k(float* __restrict__ X, __hip_bfloat16* __restrict__ Xb,
            const float* __restrict__ TB, float* __restrict__ STL,
            const float* __restrict__ g2, const float* __restrict__ b2)
{
    __shared__ float r1[256], r2[256];
    const int t = threadIdx.x;
    const int a = t & 63, rg = t >> 6;
    float s1 = 0.f, s2 = 0.f;
    for (int r = blockIdx.x*4 + rg; r < N_ATOM; r += 256){
        float v = TB[(size_t)r*AF + a];
        s1 += v; s2 += v*v;
    }
    r1[t] = s1; r2[t] = s2;
    __syncthreads();
    if (t < 64){
        s1 = r1[t]+r1[64+t]+r1[128+t]+r1[192+t];
        s2 = r2[t]+r2[64+t]+r2[128+t]+r2[192+t];
        atomicAdd(&STL[768+t], s1);
        atomicAdd(&STL[832+t], s2);
    }
    __syncthreads();
    if (t == 0){
        unsigned* cnt = (unsigned*)&STL[1200];
        __hip_atomic_fetch_add(cnt, 1u, __ATOMIC_ACQ_REL, __HIP_MEMORY_SCOPE_AGENT);
        while (__hip_atomic_load(cnt, __ATOMIC_ACQUIRE, __HIP_MEMORY_SCOPE_AGENT) < 64u)
            __builtin_amdgcn_s_sleep(2);
    }
    __syncthreads();
    float sA = __hip_atomic_load(&STL[768+a], __ATOMIC_RELAXED, __HIP_MEMORY_SCOPE_AGENT);
    float sB = __hip_atomic_load(&STL[832+a], __ATOMIC_RELAXED, __HIP_MEMORY_SCOPE_AGENT);
    float mean = sA*(1.f/N_ATOM);
    float var  = fmaxf(sB*(1.f/N_ATOM) - mean*mean, 0.f);
    float sc = g2[a]*rsqrtf(var + EPS_BN);
    float sh = b2[a] - sc*mean;
    for (int i = blockIdx.x*256 + t; i < N_ATOM*AF; i += 64*256){
        float v = softplusf_(X[i] + sc*TB[i] + sh);
        X[i]  = v;
        Xb[i] = __float2bfloat16(v);
    }
}

// ================= pooled mean per crystal + final dot
__global__ __launch_bounds__(128)
void pool_out_k(const float* __restrict__ Z, const int* __restrict__ seg,
                const float* __restrict__ outW, const float* __restrict__ outb,
                float* __restrict__ out)
{
    __shared__ float red[128];
    const int c = blockIdx.x;
    const int h = threadIdx.x;
    int l0, l1;
    {
        int l=0, r=N_ATOM;
        while (l<r){ int m=(l+r)>>1; if (seg[m] < c) l=m+1; else r=m; }
        l0 = l;
        l=l0; r=N_ATOM;
        while (l<r){ int m=(l+r)>>1; if (seg[m] < c+1) l=m+1; else r=m; }
        l1 = l;
    }
    float s = 0.f;
    for (int n = l0; n < l1; ++n) s += Z[(size_t)n*HID + h];
    float cnt = fmaxf((float)(l1-l0), 1.f);
    red[h] = (s/cnt) * outW[h];
    __syncthreads();
    for (int off=64; off>0; off>>=1){
        if (h < off) red[h] += red[h+off];
        __syncthreads();
    }
    if (h == 0) out[c] = red[0] + outb[0];
}

extern "C" void kernel_launch(void* const* d_in, const int* in_sizes, int n_in,
                              void* d_out, int out_size, void* d_ws, size_t ws_size,
                              hipStream_t stream)
{
    const float* atom_fea = (const float*)d_in[0];
    const float* nbr_fea  = (const float*)d_in[1];
    const int*   nbr_idx  = (const int*)d_in[2];
    const int*   site_seg = (const int*)d_in[3];
    const float* emb_W = (const float*)d_in[4];
    const float* emb_b = (const float*)d_in[5];
    const float* fcW   = (const float*)d_in[6];
    const float* fcb   = (const float*)d_in[7];
    const float* bn1_g = (const float*)d_in[8];
    const float* bn1_b = (const float*)d_in[9];
    const float* bn2_g = (const float*)d_in[10];
    const float* bn2_b = (const float*)d_in[11];
    const float* eW    = (const float*)d_in[12];
    const float* eb    = (const float*)d_in[13];
    const float* bne_g = (const float*)d_in[14];
    const float* bne_b = (const float*)d_in[15];
    const float* W3    = (const float*)d_in[16];
    const float* b3    = (const float*)d_in[17];
    const float* bn3_g = (const float*)d_in[18];
    const float* bn3_b = (const float*)d_in[19];
    const float* fc1W  = (const float*)d_in[20];
    const float* fc1b  = (const float*)d_in[21];
    const float* outW  = (const float*)d_in[22];
    const float* outb  = (const float*)d_in[23];

    // workspace layout (float units)
    float* ws   = (float*)d_ws;
    float* X    = ws;                          // 128,000
    float* E48  = ws + 128000;                 // 1,152,000 -> 1,280,000
    float* REST = ws + 1280000;                // 24000*512 = 12,288,000
    float* TB   = ws + 13568000;               // 128,000
    float* Z    = ws + 13696000;               // 256,000
    float* ST   = ws + 13952000;               // 3*2048 = 6,144
    //            ws + 13958144                // 1,024 spare (zeroed)
    float* SPQ  = ws + 13959168;               // 3 * 2 * 256,000 = 1,536,000
    __hip_bfloat16* WALL = (__hip_bfloat16*)(ws + 15495168); // 3*512*192 bf16
    float* BIAS = ws + 15642624;               // 1,536
    __hip_bfloat16* Xb   = (__hip_bfloat16*)(ws + 15644160); // 128,000 bf16
    __hip_bfloat16* E48b = (__hip_bfloat16*)(ws + 15708160); // 1,152,000 bf16

    {
        // flat prologue: 294,912 pack + 1,536 bias + 1,152,000 e_init + 1,543,168 zero
        const int total = 294912 + 1536 + 1152000 + 1543168;   // = 2,991,616
        prologue_k<<<total/256, 256, 0, stream>>>(fcW, eW, W3, fcb, eb, b3, nbr_fea,
                                                  WALL, BIAS, E48, E48b, ST);
    }
    emb_k<<<N_ATOM/16, 256, 0, stream>>>(atom_fea, emb_W, emb_b, X, Xb);

    for (int i = 0; i < NCONV; i++){
        float* STL = ST + i*2048;
        float* SPA = SPQ + (size_t)i*512000;
        float* SQA = SPA + 256000;

        {
            dim3 g((NM+127)/128, 4);
            gemm_fused<<<g, 256, 0, stream>>>((const unsigned short*)Xb,
                                              (const unsigned short*)E48b, nbr_idx,
                                              WALL + (size_t)i*512*LDA_T,
                                              BIAS + i*512, REST, STL, SPA, SQA);
        }
        bn3_pre<<<125, 256, 0, stream>>>(SPA, SQA, STL);
        consumer_k<<<N_ATOM, 256, 0, stream>>>(REST, STL, TB, E48, E48b,
                                               bn1_g + i*O1, bn1_b + i*O1,
                                               bne_g + i*OE, bne_b + i*OE,
                                               bn3_g + i*O1, bn3_b + i*O1);
        xupd_k<<<64, 256, 0, stream>>>(X, Xb, TB, STL,
                                       bn2_g + i*AF, bn2_b + i*AF);
    }

    // head: Z = softplus(softplus(X) @ fc1W^T + fc1b); pooled mean; out
    head_k<<<N_ATOM/16, 256, 0, stream>>>(X, fc1W, fc1b, Z);
    pool_out_k<<<NCRY, 128, 0, stream>>>(Z, site_seg, outW, outb, (float*)d_out);
}